// Round 11
// baseline (224.586 us; speedup 1.0000x reference)
//
#include <hip/hip_runtime.h>

typedef __attribute__((ext_vector_type(8))) short bf16x8;
typedef __attribute__((ext_vector_type(4))) float f32x4;
typedef __attribute__((ext_vector_type(2))) float f32x2;

__device__ __forceinline__ float leaky(float v) { return fmaxf(v, 0.01f * v); }

__device__ __forceinline__ unsigned short f2bf(float a) {
    unsigned int u = __float_as_uint(a);
    return (unsigned short)((u + 0x7FFFu + ((u >> 16) & 1u)) >> 16);
}

// RNE pack of two floats -> packed bf16x2 (HW v_cvt_pk_bf16_f32 when available)
__device__ __forceinline__ unsigned int cvtpk(float a, float b) {
#if __has_builtin(__builtin_amdgcn_cvt_pk_bf16_f32)
    typedef __attribute__((ext_vector_type(2))) __bf16 bf2_t;
    bf2_t v = __builtin_amdgcn_cvt_pk_bf16_f32(a, b);
    return __builtin_bit_cast(unsigned int, v);
#else
    unsigned int ua = __float_as_uint(a);
    ua = (ua + 0x7FFFu + ((ua >> 16) & 1u)) >> 16;
    unsigned int ub = __float_as_uint(b);
    ub = (ub + 0x7FFFu + ((ub >> 16) & 1u)) >> 16;
    return ua | (ub << 16);
#endif
}

// dword of 2 bf16 -> f32x2 (2 VALU ops)
__device__ __forceinline__ f32x2 unpk2(unsigned int d) {
    f32x2 r;
    r.x = __uint_as_float(d << 16);
    r.y = __uint_as_float(d & 0xFFFF0000u);
    return r;
}

// add + leaky + pack for one dword-pair of bf16
__device__ __forceinline__ unsigned int mix1(unsigned int u, unsigned int i) {
    f32x2 v = unpk2(u) + unpk2(i);
    v = __builtin_elementwise_max(v, v * 0.01f);
    return cvtpk(v.x, v.y);
}

// Weight prep, all in MFMA B-fragment order:
//   frag index f: j=f&7, lane=(f>>3)&63, nt=(f>>9)&7, kb=f>>12
//   n = nt*16 + (lane&15), k_frag = kb*32 + (lane>>4)*8 + j
// blocks [0,128):   WLf[f] = bf16(W_left[k_frag][n])
// blocks [128,256): WRf[f] = bf16(W_right[k_frag][n])
// blocks [256,384): Wf[f]  = bf16(W1[phi(k_frag)][n]), phi(p) = (p&7)*16 + (p>>3)
//   (phi = the feature order node_mfma2 stores u_f/i_f in; elementwise ops
//    between node output and edge GEMM input commute with phi.)
__global__ __launch_bounds__(128) void prep(const float* __restrict__ WL,
                                            const float* __restrict__ WR,
                                            const float* __restrict__ W1,
                                            unsigned short* __restrict__ WLf,
                                            unsigned short* __restrict__ WRf,
                                            unsigned short* __restrict__ Wf) {
    int g = blockIdx.x;
    int f = (g & 127) * 128 + threadIdx.x;
    int j = f & 7, lane = (f >> 3) & 63, nt = (f >> 9) & 7, kb = f >> 12;
    int n = nt * 16 + (lane & 15);
    int kf = kb * 32 + (lane >> 4) * 8 + j;
    if (g < 128) {
        WLf[f] = f2bf(WL[kf * 128 + n]);
    } else if (g < 256) {
        WRf[f] = f2bf(WR[kf * 128 + n]);
    } else {
        int k = (kf & 7) * 16 + (kf >> 3);  // phi
        Wf[f] = f2bf(W1[k * 128 + n]);
    }
}

#define PITCH 136  // bf16 elems per LDS row

// Both node linears: out = bf16(h @ W + b), stored in phi-order (pos p=col*8+nt
// holds logical n=nt*16+col). Edge-kernel-shaped for occupancy: 512 thr = 8
// waves, 128 rows/block, col-split wave pairs -> 34.8 KB LDS, 4 blocks/CU =
// 32 waves/CU (node was 50%-occupancy bound at 256 thr; ~95 us vs ~30 roofline).
__global__ __launch_bounds__(512, 8) void node_mfma2(const float* __restrict__ h_user,
                                                     const float* __restrict__ h_item,
                                                     const unsigned short* __restrict__ WLf,
                                                     const unsigned short* __restrict__ WRf,
                                                     const float* __restrict__ b_left,
                                                     const float* __restrict__ b_right,
                                                     unsigned short* __restrict__ u_f,
                                                     unsigned short* __restrict__ i_f,
                                                     int N_U, int N_I, int BU) {
    bool isU = (int)blockIdx.x < BU;
    const float* h = isU ? h_user : h_item;
    const unsigned short* Wfr = isU ? WLf : WRf;
    const float* b = isU ? b_left : b_right;
    unsigned short* out = isU ? u_f : i_f;
    int N = isU ? N_U : N_I;
    int r0 = (isU ? blockIdx.x : blockIdx.x - BU) * 128;

    __shared__ unsigned short xt[128 * PITCH];
    int t = threadIdx.x;
    int s = t & 31;    // float4 segment within row (32 per row)
    int el0 = t >> 5;  // 0..15

    // ---- batched stage: 8 coalesced float4 loads in one vmcnt window ----
    f32x4 g[8];
#pragma unroll
    for (int pass = 0; pass < 8; ++pass) {
        int row = min(r0 + pass * 16 + el0, N - 1);
        g[pass] = *(const f32x4*)(h + (size_t)row * 128 + s * 4);
    }
#pragma unroll
    for (int pass = 0; pass < 8; ++pass) {
        int el = pass * 16 + el0;
        unsigned int* rp = (unsigned int*)(xt + el * PITCH + s * 4);
        rp[0] = cvtpk(g[pass].x, g[pass].y);
        rp[1] = cvtpk(g[pass].z, g[pass].w);
    }
    __syncthreads();

    // ---- MFMA: wave w -> rows [32*(w>>1), +32), cols [64*(w&1), +64) ----
    int wave = t >> 6;
    int lane = t & 63;
    int col = lane & 15;
    int quad = lane >> 4;
    int wp = wave >> 1;
    int ch = wave & 1;
    int m0 = wp * 32;

    f32x4 acc[2][4];
#pragma unroll
    for (int mt = 0; mt < 2; ++mt)
#pragma unroll
        for (int i = 0; i < 4; ++i) acc[mt][i] = (f32x4){0.f, 0.f, 0.f, 0.f};

#pragma unroll
    for (int kb = 0; kb < 4; ++kb) {
        bf16x8 afr[2];
#pragma unroll
        for (int mt = 0; mt < 2; ++mt)
            afr[mt] = *(const bf16x8*)(xt + (m0 + mt * 16 + col) * PITCH + kb * 32 + quad * 8);
#pragma unroll
        for (int i = 0; i < 4; ++i) {
            int nt = ch * 4 + i;
            bf16x8 bfr = *(const bf16x8*)(Wfr + ((kb * 8 + nt) * 64 + lane) * 8);
            acc[0][i] = __builtin_amdgcn_mfma_f32_16x16x32_bf16(afr[0], bfr, acc[0][i], 0, 0, 0);
            acc[1][i] = __builtin_amdgcn_mfma_f32_16x16x32_bf16(afr[1], bfr, acc[1][i], 0, 0, 0);
        }
    }

    // ---- epilogue: 4 nt-values per lane -> one 8B phi-layout store ----
    float bb[4];
#pragma unroll
    for (int i = 0; i < 4; ++i) bb[i] = b[(ch * 4 + i) * 16 + col];
#pragma unroll
    for (int mt = 0; mt < 2; ++mt)
#pragma unroll
        for (int rr = 0; rr < 4; ++rr) {
            int row = r0 + m0 + mt * 16 + quad * 4 + rr;
            uint2 v;
            v.x = cvtpk(acc[mt][0][rr] + bb[0], acc[mt][1][rr] + bb[1]);
            v.y = cvtpk(acc[mt][2][rr] + bb[2], acc[mt][3][rr] + bb[3]);
            if (row < N) *(uint2*)(out + (size_t)row * 128 + col * 8 + ch * 4) = v;
        }
}

// Edge kernel (r6/r10 structure -- best measured ~98 us): 512 threads = 8 waves,
// 128 edges/block, col-split wave pairs. Wave w: edges [32*(w>>1), +32),
// cols [64*(w&1), +64). 34.8 KB LDS -> 4 blocks/CU.
#define TE 128

__global__ __launch_bounds__(512, 8) void edge_kernel(
    const unsigned short* __restrict__ u_f, const unsigned short* __restrict__ i_f,
    const int* __restrict__ src, const int* __restrict__ dst,
    const unsigned short* __restrict__ Wf,
    const float* __restrict__ b1, const float* __restrict__ W2,
    const float* __restrict__ b2, float* __restrict__ out, int E) {
    __shared__ unsigned short xt[TE * PITCH];
    __shared__ float zb[4][2][32];
    int t = threadIdx.x;
    int e0 = blockIdx.x * TE;

    // ---- stage: 16 threads per edge (one 16B segment each), 4 passes ----
    int s = t & 15;
    int el0 = t >> 4;  // 0..31
#pragma unroll
    for (int pass = 0; pass < 4; ++pass) {
        int el = pass * 32 + el0;
        int ec = min(e0 + el, E - 1);
        uint4 u4 = *(const uint4*)(u_f + (size_t)src[ec] * 128 + s * 8);
        uint4 i4 = *(const uint4*)(i_f + (size_t)dst[ec] * 128 + s * 8);
        uint4 a;
        a.x = mix1(u4.x, i4.x);
        a.y = mix1(u4.y, i4.y);
        a.z = mix1(u4.z, i4.z);
        a.w = mix1(u4.w, i4.w);
        *(uint4*)(xt + el * PITCH + s * 8) = a;
    }
    __syncthreads();

    // ---- MFMA: wave handles 32 edges x 64 cols ----
    int wave = t >> 6;
    int lane = t & 63;
    int col = lane & 15;
    int quad = lane >> 4;
    int wp = wave >> 1;   // wave pair -> edge group
    int ch = wave & 1;    // col half
    int m0 = wp * 32;

    f32x4 acc[2][4];
#pragma unroll
    for (int mt = 0; mt < 2; ++mt)
#pragma unroll
        for (int i = 0; i < 4; ++i) acc[mt][i] = (f32x4){0.f, 0.f, 0.f, 0.f};

#pragma unroll
    for (int kb = 0; kb < 4; ++kb) {
        bf16x8 afr[2];
#pragma unroll
        for (int mt = 0; mt < 2; ++mt)
            afr[mt] = *(const bf16x8*)(xt + (m0 + mt * 16 + col) * PITCH + kb * 32 + quad * 8);
#pragma unroll
        for (int i = 0; i < 4; ++i) {
            int nt = ch * 4 + i;
            bf16x8 bfr = *(const bf16x8*)(Wf + ((kb * 8 + nt) * 64 + lane) * 8);
            acc[0][i] = __builtin_amdgcn_mfma_f32_16x16x32_bf16(afr[0], bfr, acc[0][i], 0, 0, 0);
            acc[1][i] = __builtin_amdgcn_mfma_f32_16x16x32_bf16(afr[1], bfr, acc[1][i], 0, 0, 0);
        }
    }

    // ---- epilogue: partial z over this wave's 64 cols (vector over rr) ----
    f32x4 p[2];
#pragma unroll
    for (int mt = 0; mt < 2; ++mt) p[mt] = (f32x4){0.f, 0.f, 0.f, 0.f};

#pragma unroll
    for (int i = 0; i < 4; ++i) {
        int n = (ch * 4 + i) * 16 + col;
        float bb = b1[n];
        float ww = W2[n];
#pragma unroll
        for (int mt = 0; mt < 2; ++mt) {
            f32x4 y = acc[mt][i] + bb;
            y = __builtin_elementwise_max(y, y * 0.01f);
            p[mt] += y * ww;
        }
    }
#pragma unroll
    for (int off = 1; off < 16; off <<= 1)
#pragma unroll
        for (int mt = 0; mt < 2; ++mt)
#pragma unroll
            for (int rr = 0; rr < 4; ++rr) p[mt][rr] += __shfl_xor(p[mt][rr], off, 64);

    if (col == 0) {
#pragma unroll
        for (int mt = 0; mt < 2; ++mt)
#pragma unroll
            for (int rr = 0; rr < 4; ++rr)
                zb[wp][ch][mt * 16 + quad * 4 + rr] = p[mt][rr];
    }
    __syncthreads();

    if (t < 128) {
        int g = t >> 5;       // wave pair
        int idx = t & 31;     // edge within pair
        float z = zb[g][0][idx] + zb[g][1][idx] + b2[0];
        int e = e0 + g * 32 + idx;
        if (e < E) out[e] = leaky(z);
    }
}

extern "C" void kernel_launch(void* const* d_in, const int* in_sizes, int n_in,
                              void* d_out, int out_size, void* d_ws, size_t ws_size,
                              hipStream_t stream) {
    const float* h_user  = (const float*)d_in[0];
    const float* h_item  = (const float*)d_in[1];
    const int*   src_idx = (const int*)d_in[2];
    const int*   dst_idx = (const int*)d_in[3];
    const float* W_left  = (const float*)d_in[4];
    const float* b_left  = (const float*)d_in[5];
    const float* W_right = (const float*)d_in[6];
    const float* b_right = (const float*)d_in[7];
    const float* W1      = (const float*)d_in[8];
    const float* b1      = (const float*)d_in[9];
    const float* W2      = (const float*)d_in[10];
    const float* b2      = (const float*)d_in[11];
    float* out = (float*)d_out;

    int N_U = in_sizes[0] / 128;
    int N_I = in_sizes[1] / 128;
    int E   = in_sizes[2];

    // Workspace: [Wf 32KB][WLf 32KB][WRf 32KB][pad to 128KB][u_f bf16][i_f bf16]
    unsigned short* Wf  = (unsigned short*)d_ws;
    unsigned short* WLf = Wf + 16384;
    unsigned short* WRf = WLf + 16384;
    unsigned short* u_f = (unsigned short*)((char*)d_ws + 131072);
    unsigned short* i_f = u_f + (size_t)N_U * 128;

    prep<<<384, 128, 0, stream>>>(W_left, W_right, W1, WLf, WRf, Wf);

    int BU = (N_U + 127) / 128;
    int BI = (N_I + 127) / 128;
    node_mfma2<<<BU + BI, 512, 0, stream>>>(h_user, h_item, WLf, WRf, b_left, b_right,
                                            u_f, i_f, N_U, N_I, BU);

    edge_kernel<<<(E + TE - 1) / TE, 512, 0, stream>>>(u_f, i_f, src_idx, dst_idx,
                                                       Wf, b1, W2, b2, out, E);
}

// Round 12
// 222.398 us; speedup vs baseline: 1.0098x; 1.0098x over previous
//
#include <hip/hip_runtime.h>

typedef __attribute__((ext_vector_type(8))) short bf16x8;
typedef __attribute__((ext_vector_type(4))) float f32x4;
typedef __attribute__((ext_vector_type(2))) float f32x2;

__device__ __forceinline__ float leaky(float v) { return fmaxf(v, 0.01f * v); }

__device__ __forceinline__ unsigned short f2bf(float a) {
    unsigned int u = __float_as_uint(a);
    return (unsigned short)((u + 0x7FFFu + ((u >> 16) & 1u)) >> 16);
}

// RNE pack of two floats -> packed bf16x2 (HW v_cvt_pk_bf16_f32 when available)
__device__ __forceinline__ unsigned int cvtpk(float a, float b) {
#if __has_builtin(__builtin_amdgcn_cvt_pk_bf16_f32)
    typedef __attribute__((ext_vector_type(2))) __bf16 bf2_t;
    bf2_t v = __builtin_amdgcn_cvt_pk_bf16_f32(a, b);
    return __builtin_bit_cast(unsigned int, v);
#else
    unsigned int ua = __float_as_uint(a);
    ua = (ua + 0x7FFFu + ((ua >> 16) & 1u)) >> 16;
    unsigned int ub = __float_as_uint(b);
    ub = (ub + 0x7FFFu + ((ub >> 16) & 1u)) >> 16;
    return ua | (ub << 16);
#endif
}

// dword of 2 bf16 -> f32x2 (2 VALU ops)
__device__ __forceinline__ f32x2 unpk2(unsigned int d) {
    f32x2 r;
    r.x = __uint_as_float(d << 16);
    r.y = __uint_as_float(d & 0xFFFF0000u);
    return r;
}

// add + leaky + pack for one dword-pair of bf16
__device__ __forceinline__ unsigned int mix1(unsigned int u, unsigned int i) {
    f32x2 v = unpk2(u) + unpk2(i);
    v = __builtin_elementwise_max(v, v * 0.01f);
    return cvtpk(v.x, v.y);
}

// Weight prep, all in MFMA B-fragment order:
//   frag index f: j=f&7, lane=(f>>3)&63, nt=(f>>9)&7, kb=f>>12
//   n = nt*16 + (lane&15), k_frag = kb*32 + (lane>>4)*8 + j
// blocks [0,128):   WLf[f] = bf16(W_left[k_frag][n])
// blocks [128,256): WRf[f] = bf16(W_right[k_frag][n])
// blocks [256,384): Wf[f]  = bf16(W1[phi(k_frag)][n]), phi(p) = (p&7)*16 + (p>>3)
//   (phi = the feature order node_mfma2 stores u_f/i_f in; elementwise ops
//    between node output and edge GEMM input commute with phi.)
__global__ __launch_bounds__(128) void prep(const float* __restrict__ WL,
                                            const float* __restrict__ WR,
                                            const float* __restrict__ W1,
                                            unsigned short* __restrict__ WLf,
                                            unsigned short* __restrict__ WRf,
                                            unsigned short* __restrict__ Wf) {
    int g = blockIdx.x;
    int f = (g & 127) * 128 + threadIdx.x;
    int j = f & 7, lane = (f >> 3) & 63, nt = (f >> 9) & 7, kb = f >> 12;
    int n = nt * 16 + (lane & 15);
    int kf = kb * 32 + (lane >> 4) * 8 + j;
    if (g < 128) {
        WLf[f] = f2bf(WL[kf * 128 + n]);
    } else if (g < 256) {
        WRf[f] = f2bf(WR[kf * 128 + n]);
    } else {
        int k = (kf & 7) * 16 + (kf >> 3);  // phi
        Wf[f] = f2bf(W1[k * 128 + n]);
    }
}

#define PITCH 136  // bf16 elems per LDS row

// Both node linears: out = bf16(h @ W + b), stored in phi-order (pos p=col*8+nt
// holds logical n=nt*16+col). 512 thr = 8 waves, 128 rows/block, col-split
// wave pairs; 34.8 KB LDS -> 4 blocks/CU.
__global__ __launch_bounds__(512, 8) void node_mfma2(const float* __restrict__ h_user,
                                                     const float* __restrict__ h_item,
                                                     const unsigned short* __restrict__ WLf,
                                                     const unsigned short* __restrict__ WRf,
                                                     const float* __restrict__ b_left,
                                                     const float* __restrict__ b_right,
                                                     unsigned short* __restrict__ u_f,
                                                     unsigned short* __restrict__ i_f,
                                                     int N_U, int N_I, int BU) {
    bool isU = (int)blockIdx.x < BU;
    const float* h = isU ? h_user : h_item;
    const unsigned short* Wfr = isU ? WLf : WRf;
    const float* b = isU ? b_left : b_right;
    unsigned short* out = isU ? u_f : i_f;
    int N = isU ? N_U : N_I;
    int r0 = (isU ? blockIdx.x : blockIdx.x - BU) * 128;

    __shared__ unsigned short xt[128 * PITCH];
    int t = threadIdx.x;
    int s = t & 31;    // float4 segment within row (32 per row)
    int el0 = t >> 5;  // 0..15

    // ---- batched stage: 8 coalesced float4 loads in one vmcnt window ----
    f32x4 g[8];
#pragma unroll
    for (int pass = 0; pass < 8; ++pass) {
        int row = min(r0 + pass * 16 + el0, N - 1);
        g[pass] = *(const f32x4*)(h + (size_t)row * 128 + s * 4);
    }
#pragma unroll
    for (int pass = 0; pass < 8; ++pass) {
        int el = pass * 16 + el0;
        unsigned int* rp = (unsigned int*)(xt + el * PITCH + s * 4);
        rp[0] = cvtpk(g[pass].x, g[pass].y);
        rp[1] = cvtpk(g[pass].z, g[pass].w);
    }
    __syncthreads();

    // ---- MFMA: wave w -> rows [32*(w>>1), +32), cols [64*(w&1), +64) ----
    int wave = t >> 6;
    int lane = t & 63;
    int col = lane & 15;
    int quad = lane >> 4;
    int wp = wave >> 1;
    int ch = wave & 1;
    int m0 = wp * 32;

    f32x4 acc[2][4];
#pragma unroll
    for (int mt = 0; mt < 2; ++mt)
#pragma unroll
        for (int i = 0; i < 4; ++i) acc[mt][i] = (f32x4){0.f, 0.f, 0.f, 0.f};

#pragma unroll
    for (int kb = 0; kb < 4; ++kb) {
        bf16x8 afr[2];
#pragma unroll
        for (int mt = 0; mt < 2; ++mt)
            afr[mt] = *(const bf16x8*)(xt + (m0 + mt * 16 + col) * PITCH + kb * 32 + quad * 8);
#pragma unroll
        for (int i = 0; i < 4; ++i) {
            int nt = ch * 4 + i;
            bf16x8 bfr = *(const bf16x8*)(Wfr + ((kb * 8 + nt) * 64 + lane) * 8);
            acc[0][i] = __builtin_amdgcn_mfma_f32_16x16x32_bf16(afr[0], bfr, acc[0][i], 0, 0, 0);
            acc[1][i] = __builtin_amdgcn_mfma_f32_16x16x32_bf16(afr[1], bfr, acc[1][i], 0, 0, 0);
        }
    }

    // ---- epilogue: 4 nt-values per lane -> one 8B phi-layout store ----
    float bb[4];
#pragma unroll
    for (int i = 0; i < 4; ++i) bb[i] = b[(ch * 4 + i) * 16 + col];
#pragma unroll
    for (int mt = 0; mt < 2; ++mt)
#pragma unroll
        for (int rr = 0; rr < 4; ++rr) {
            int row = r0 + m0 + mt * 16 + quad * 4 + rr;
            uint2 v;
            v.x = cvtpk(acc[mt][0][rr] + bb[0], acc[mt][1][rr] + bb[1]);
            v.y = cvtpk(acc[mt][2][rr] + bb[2], acc[mt][3][rr] + bb[3]);
            if (row < N) *(uint2*)(out + (size_t)row * 128 + col * 8 + ch * 4) = v;
        }
}

// Edge kernel: 512 threads = 8 waves, 128 edges/block, col-split wave pairs.
// launch_bounds(512,6): 85-VGPR cap (3 blocks/CU, 75% occ) so the staging
// batch windows can be honored -- at (512,8)'s 64-cap the compiler serialized
// staging into 8 dependent MALL-latency round trips (VGPR_Count=32, r8/r10).
// Staging = two explicit windows: 8 index loads, then 8 uint4 gathers.
#define TE 128

__global__ __launch_bounds__(512, 6) void edge_kernel(
    const unsigned short* __restrict__ u_f, const unsigned short* __restrict__ i_f,
    const int* __restrict__ src, const int* __restrict__ dst,
    const unsigned short* __restrict__ Wf,
    const float* __restrict__ b1, const float* __restrict__ W2,
    const float* __restrict__ b2, float* __restrict__ out, int E) {
    __shared__ unsigned short xt[TE * PITCH];
    __shared__ float zb[4][2][32];
    int t = threadIdx.x;
    int e0 = blockIdx.x * TE;

    // ---- stage: 16 threads per edge (one 16B segment each), 4 passes ----
    int s = t & 15;
    int el0 = t >> 4;  // 0..31

    // window 1: all 8 index loads
    int su[4], sd[4];
#pragma unroll
    for (int pass = 0; pass < 4; ++pass) {
        int ec = min(e0 + pass * 32 + el0, E - 1);
        su[pass] = src[ec];
        sd[pass] = dst[ec];
    }
    // window 2: all 8 feature gathers
    uint4 ug[4], ig[4];
#pragma unroll
    for (int pass = 0; pass < 4; ++pass) {
        ug[pass] = *(const uint4*)(u_f + (size_t)su[pass] * 128 + s * 8);
        ig[pass] = *(const uint4*)(i_f + (size_t)sd[pass] * 128 + s * 8);
    }
    // mix + LDS
#pragma unroll
    for (int pass = 0; pass < 4; ++pass) {
        uint4 a;
        a.x = mix1(ug[pass].x, ig[pass].x);
        a.y = mix1(ug[pass].y, ig[pass].y);
        a.z = mix1(ug[pass].z, ig[pass].z);
        a.w = mix1(ug[pass].w, ig[pass].w);
        *(uint4*)(xt + (pass * 32 + el0) * PITCH + s * 8) = a;
    }
    __syncthreads();

    // ---- MFMA: wave handles 32 edges x 64 cols ----
    int wave = t >> 6;
    int lane = t & 63;
    int col = lane & 15;
    int quad = lane >> 4;
    int wp = wave >> 1;   // wave pair -> edge group
    int ch = wave & 1;    // col half
    int m0 = wp * 32;

    f32x4 acc[2][4];
#pragma unroll
    for (int mt = 0; mt < 2; ++mt)
#pragma unroll
        for (int i = 0; i < 4; ++i) acc[mt][i] = (f32x4){0.f, 0.f, 0.f, 0.f};

#pragma unroll
    for (int kb = 0; kb < 4; ++kb) {
        bf16x8 afr[2];
#pragma unroll
        for (int mt = 0; mt < 2; ++mt)
            afr[mt] = *(const bf16x8*)(xt + (m0 + mt * 16 + col) * PITCH + kb * 32 + quad * 8);
#pragma unroll
        for (int i = 0; i < 4; ++i) {
            int nt = ch * 4 + i;
            bf16x8 bfr = *(const bf16x8*)(Wf + ((kb * 8 + nt) * 64 + lane) * 8);
            acc[0][i] = __builtin_amdgcn_mfma_f32_16x16x32_bf16(afr[0], bfr, acc[0][i], 0, 0, 0);
            acc[1][i] = __builtin_amdgcn_mfma_f32_16x16x32_bf16(afr[1], bfr, acc[1][i], 0, 0, 0);
        }
    }

    // ---- epilogue: partial z over this wave's 64 cols (vector over rr) ----
    f32x4 p[2];
#pragma unroll
    for (int mt = 0; mt < 2; ++mt) p[mt] = (f32x4){0.f, 0.f, 0.f, 0.f};

#pragma unroll
    for (int i = 0; i < 4; ++i) {
        int n = (ch * 4 + i) * 16 + col;
        float bb = b1[n];
        float ww = W2[n];
#pragma unroll
        for (int mt = 0; mt < 2; ++mt) {
            f32x4 y = acc[mt][i] + bb;
            y = __builtin_elementwise_max(y, y * 0.01f);
            p[mt] += y * ww;
        }
    }
#pragma unroll
    for (int off = 1; off < 16; off <<= 1)
#pragma unroll
        for (int mt = 0; mt < 2; ++mt)
#pragma unroll
            for (int rr = 0; rr < 4; ++rr) p[mt][rr] += __shfl_xor(p[mt][rr], off, 64);

    if (col == 0) {
#pragma unroll
        for (int mt = 0; mt < 2; ++mt)
#pragma unroll
            for (int rr = 0; rr < 4; ++rr)
                zb[wp][ch][mt * 16 + quad * 4 + rr] = p[mt][rr];
    }
    __syncthreads();

    if (t < 128) {
        int g = t >> 5;       // wave pair
        int idx = t & 31;     // edge within pair
        float z = zb[g][0][idx] + zb[g][1][idx] + b2[0];
        int e = e0 + g * 32 + idx;
        if (e < E) out[e] = leaky(z);
    }
}

extern "C" void kernel_launch(void* const* d_in, const int* in_sizes, int n_in,
                              void* d_out, int out_size, void* d_ws, size_t ws_size,
                              hipStream_t stream) {
    const float* h_user  = (const float*)d_in[0];
    const float* h_item  = (const float*)d_in[1];
    const int*   src_idx = (const int*)d_in[2];
    const int*   dst_idx = (const int*)d_in[3];
    const float* W_left  = (const float*)d_in[4];
    const float* b_left  = (const float*)d_in[5];
    const float* W_right = (const float*)d_in[6];
    const float* b_right = (const float*)d_in[7];
    const float* W1      = (const float*)d_in[8];
    const float* b1      = (const float*)d_in[9];
    const float* W2      = (const float*)d_in[10];
    const float* b2      = (const float*)d_in[11];
    float* out = (float*)d_out;

    int N_U = in_sizes[0] / 128;
    int N_I = in_sizes[1] / 128;
    int E   = in_sizes[2];

    // Workspace: [Wf 32KB][WLf 32KB][WRf 32KB][pad to 128KB][u_f bf16][i_f bf16]
    unsigned short* Wf  = (unsigned short*)d_ws;
    unsigned short* WLf = Wf + 16384;
    unsigned short* WRf = WLf + 16384;
    unsigned short* u_f = (unsigned short*)((char*)d_ws + 131072);
    unsigned short* i_f = u_f + (size_t)N_U * 128;

    prep<<<384, 128, 0, stream>>>(W_left, W_right, W1, WLf, WRf, Wf);

    int BU = (N_U + 127) / 128;
    int BI = (N_I + 127) / 128;
    node_mfma2<<<BU + BI, 512, 0, stream>>>(h_user, h_item, WLf, WRf, b_left, b_right,
                                            u_f, i_f, N_U, N_I, BU);

    edge_kernel<<<(E + TE - 1) / TE, 512, 0, stream>>>(u_f, i_f, src_idx, dst_idx,
                                                       Wf, b1, W2, b2, out, E);
}